// Round 1
// baseline (111.049 us; speedup 1.0000x reference)
//
#include <hip/hip_runtime.h>

// LSTM fused forward: B=131072, T=48, I=5, H=8, classes=2.
// 8 lanes per batch element (lane = hidden unit j), 32 elems / 256-thread block.

#define T 48
#define ISZ 5
#define HID 8
#define EPB 32            // batch elems per block
#define THREADS 256
#define XROW (T * ISZ)    // 240 floats per elem
#define XPAD 244          // padded row stride (bank-conflict-free, 16B-aligned rows)

#if __has_builtin(__builtin_amdgcn_exp2f)
#define EXP2F(x) __builtin_amdgcn_exp2f(x)
#else
#define EXP2F(x) exp2f(x)
#endif
#if __has_builtin(__builtin_amdgcn_rcpf)
#define RCPF(x) __builtin_amdgcn_rcpf(x)
#else
#define RCPF(x) (1.0f / (x))
#endif

__device__ __forceinline__ float sigm(float v) {
    return RCPF(1.0f + EXP2F(-1.44269504f * v));
}
__device__ __forceinline__ float tanh_(float v) {
    return 1.0f - 2.0f * RCPF(1.0f + EXP2F(2.88539008f * v));
}

__global__ __launch_bounds__(THREADS) void lstm_fused(
    const float* __restrict__ x, const float* __restrict__ W_ih,
    const float* __restrict__ W_hh, const float* __restrict__ b_ih,
    const float* __restrict__ b_hh, const float* __restrict__ W_fc,
    const float* __restrict__ b_fc, float* __restrict__ out)
{
    __shared__ __align__(16) float s_x[EPB * XPAD];
    __shared__ __align__(16) float s_wih[32 * ISZ];
    __shared__ __align__(16) float s_whh[32 * HID];
    __shared__ __align__(16) float s_bias[32];
    __shared__ __align__(16) float s_wfcT[8 * 100];   // [j][t*2+k], pad 96->100
    __shared__ __align__(16) float s_h[EPB][HID];

    const int tid = threadIdx.x;
    const int r = tid >> 3;      // elem row in block
    const int j = tid & 7;       // hidden unit

    // ---- stage weights ----
    for (int i = tid; i < 32 * ISZ; i += THREADS) s_wih[i] = W_ih[i];
    for (int i = tid; i < 32 * HID; i += THREADS) s_whh[i] = W_hh[i];
    if (tid < 32) s_bias[tid] = b_ih[tid] + b_hh[tid];
    for (int i = tid; i < 2 * T * HID; i += THREADS) {
        int k = (i >= T * HID) ? 1 : 0;
        int rem = i - k * T * HID;
        int t = rem >> 3, jj = rem & 7;
        s_wfcT[jj * 100 + t * 2 + k] = W_fc[i];
    }
    // ---- stage x (block's 32 elems are contiguous: 7680 floats) ----
    {
        const float4* xg = (const float4*)(x + (size_t)blockIdx.x * (EPB * XROW));
        #pragma unroll
        for (int it = 0; it < (EPB * XROW / 4 + THREADS - 1) / THREADS; ++it) {
            int q = it * THREADS + tid;
            if (q < EPB * XROW / 4) {
                float4 v = xg[q];
                int lin = q << 2;
                int row = lin / XROW;
                int col = lin - row * XROW;
                *(float4*)&s_x[row * XPAD + col] = v;
            }
        }
    }
    s_h[r][j] = 0.0f;
    __syncthreads();

    // ---- hoist this lane's weights into registers ----
    float wih[4][5], whh[4][8], bias[4];
    #pragma unroll
    for (int g = 0; g < 4; ++g) {
        int row = g * 8 + j;    // gate order i,f,g,o
        #pragma unroll
        for (int i = 0; i < 5; ++i) wih[g][i] = s_wih[row * 5 + i];
        #pragma unroll
        for (int k = 0; k < 8; ++k) whh[g][k] = s_whh[row * 8 + k];
        bias[g] = s_bias[row];
    }

    float h = 0.0f, c = 0.0f, acc0 = 0.0f, acc1 = 0.0f;
    const float* xr = &s_x[r * XPAD];
    const float* wfr = &s_wfcT[j * 100];

    #pragma unroll 1
    for (int t4 = 0; t4 < T / 4; ++t4) {
        // 4 timesteps of x for this elem: 20 floats, 16B-aligned
        float xs[20];
        #pragma unroll
        for (int q = 0; q < 5; ++q)
            *(float4*)&xs[q * 4] = *(const float4*)&xr[t4 * 20 + q * 4];
        // 4 timesteps of this lane's FC weights: 8 floats
        float wf[8];
        #pragma unroll
        for (int q = 0; q < 2; ++q)
            *(float4*)&wf[q * 4] = *(const float4*)&wfr[t4 * 8 + q * 4];

        #pragma unroll
        for (int u = 0; u < 4; ++u) {
            // broadcast all 8 h's of this elem (written last step, same wave)
            float hk[8];
            *(float4*)&hk[0] = *(const float4*)&s_h[r][0];
            *(float4*)&hk[4] = *(const float4*)&s_h[r][4];

            float pre[4];
            #pragma unroll
            for (int g = 0; g < 4; ++g) {
                float s = bias[g];
                #pragma unroll
                for (int i = 0; i < 5; ++i) s = fmaf(wih[g][i], xs[u * 5 + i], s);
                #pragma unroll
                for (int k = 0; k < 8; ++k) s = fmaf(whh[g][k], hk[k], s);
                pre[g] = s;
            }
            float ig = sigm(pre[0]);
            float fg = sigm(pre[1]);
            float gg = tanh_(pre[2]);
            float og = sigm(pre[3]);
            c = fmaf(fg, c, ig * gg);
            h = og * tanh_(c);
            s_h[r][j] = h;

            acc0 = fmaf(wf[u * 2 + 0], h, acc0);
            acc1 = fmaf(wf[u * 2 + 1], h, acc1);
        }
    }

    // ---- reduce partial FC sums across the 8-lane group ----
    #pragma unroll
    for (int m = 4; m >= 1; m >>= 1) {
        acc0 += __shfl_xor(acc0, m, 8);
        acc1 += __shfl_xor(acc1, m, 8);
    }
    if (j == 0) {
        const int b = blockIdx.x * EPB + r;
        float2 o;
        o.x = acc0 + b_fc[0];
        o.y = acc1 + b_fc[1];
        *(float2*)&out[(size_t)b * 2] = o;
    }
}

extern "C" void kernel_launch(void* const* d_in, const int* in_sizes, int n_in,
                              void* d_out, int out_size, void* d_ws, size_t ws_size,
                              hipStream_t stream) {
    const float* x    = (const float*)d_in[0];
    const float* W_ih = (const float*)d_in[1];
    const float* W_hh = (const float*)d_in[2];
    const float* b_ih = (const float*)d_in[3];
    const float* b_hh = (const float*)d_in[4];
    const float* W_fc = (const float*)d_in[5];
    const float* b_fc = (const float*)d_in[6];
    float* out = (float*)d_out;

    const int B = in_sizes[0] / XROW;       // 131072
    dim3 grid(B / EPB), block(THREADS);
    lstm_fused<<<grid, block, 0, stream>>>(x, W_ih, W_hh, b_ih, b_hh, W_fc, b_fc, out);
}

// Round 3
// 89.266 us; speedup vs baseline: 1.2440x; 1.2440x over previous
//
#include <hip/hip_runtime.h>

// LSTM fused forward: B=131072, T=48, I=5, H=8, classes=2.
// MFMA formulation with hi/lo double-bf16 precision:
//   A (16x32): k0-15 = W_hi (x cols 0-4, h cols 8-15), k16-31 = W_lo (same).
//   pass1: B = [B_hi | B_hi] ; pass2: B = [B_lo | B_lo] accumulated.
//   => exact W*(B_hi+B_lo) with fp32 accumulation (effectively fp32 recurrence).
// Per wave: 16 elems; each lane owns units (2*grp, 2*grp+1) of elem (lane&15).
// h feeds back via wave-private LDS rows (wave-lockstep, no barriers in loop).
// x staged per-wave in chunks of 8 timesteps, double-buffered.

#define T 48
#define CH 8
#define NCH (T / CH)
#define EPW 16
#define WPB 2
#define EPB (EPW * WPB)
#define THREADS (64 * WPB)

typedef __attribute__((ext_vector_type(8))) short short8v;
typedef __attribute__((ext_vector_type(4))) float f32x4;
typedef __attribute__((ext_vector_type(4))) unsigned u32x4;

#if __has_builtin(__builtin_amdgcn_exp2f)
#define EXP2F(x) __builtin_amdgcn_exp2f(x)
#else
#define EXP2F(x) exp2f(x)
#endif
#if __has_builtin(__builtin_amdgcn_rcpf)
#define RCPF(x) __builtin_amdgcn_rcpf(x)
#else
#define RCPF(x) (1.0f / (x))
#endif

#define SCL_SIG  (-1.44269504f)   // sigmoid gates: e = 2^(scl*v)
#define SCL_TANH (-2.88539008f)   // tanh gates:    q = 2^(scl*v)

__device__ __forceinline__ unsigned short f2bf(float f) {
    unsigned u = __float_as_uint(f);
    return (unsigned short)((u + 0x7FFFu + ((u >> 16) & 1u)) >> 16);
}
__device__ __forceinline__ float bf2f(unsigned short b) {
    return __uint_as_float((unsigned)b << 16);
}

// ei,ef,qg,eo are 2^(scaled pre-acts). i=1/(1+ei), f=1/(1+ef),
// g=(1-qg)/(1+qg), o=1/(1+eo); c'=f*c+i*g; h=o*tanh(c').
__device__ __forceinline__ void unitstep(float ei, float ef, float qg, float eo,
                                         float& c, float& h) {
    float Ai = 1.0f + ei, Af = 1.0f + ef, Ag = 1.0f + qg, Ao = 1.0f + eo;
    float P  = Ai * Ag;
    float R  = RCPF(P * Af);
    float num = fmaf(c, P, (2.0f - Ag) * Af);   // c*Ai*Ag + (1-qg)*Af
    c = num * R;                                // = f*c + i*g
    float qc = EXP2F(c * SCL_TANH);
    float Wc = 1.0f + qc;
    float Rh = RCPF(Wc * Ao);
    h = (2.0f - Wc) * Rh;                       // = tanh(c') * o
}

__global__ __launch_bounds__(THREADS) void lstm_mfma(
    const float* __restrict__ x, const float* __restrict__ W_ih,
    const float* __restrict__ W_hh, const float* __restrict__ b_ih,
    const float* __restrict__ b_hh, const float* __restrict__ W_fc,
    const float* __restrict__ b_fc, float* __restrict__ out)
{
    __shared__ __align__(16) unsigned short s_xh[WPB][2][CH][EPW][8];
    __shared__ __align__(16) unsigned short s_xl[WPB][2][CH][EPW][8];
    __shared__ __align__(16) unsigned short s_hh[WPB][EPW][8];
    __shared__ __align__(16) unsigned short s_hl[WPB][EPW][8];
    __shared__ __align__(16) float s_wfc[T][4][4];

    const int tid  = threadIdx.x;
    const int wv   = tid >> 6;
    const int lane = tid & 63;
    const int e    = lane & 15;     // elem col (B/C) and A-row index
    const int grp  = lane >> 4;

    // ---- zero wave-private LDS (x pads + h state) ----
    {
        u32x4 z = {0u, 0u, 0u, 0u};
        u32x4* zh = (u32x4*)&s_xh[wv][0][0][0][0];
        u32x4* zl = (u32x4*)&s_xl[wv][0][0][0][0];
        #pragma unroll
        for (int q = 0; q < 4; ++q) { zh[q * 64 + lane] = z; zl[q * 64 + lane] = z; }
        ((unsigned*)&s_hh[wv][0][0])[lane] = 0u;
        ((unsigned*)&s_hl[wv][0][0])[lane] = 0u;
    }
    // ---- stage W_fc rearranged: s_wfc[t][g][j] = W_fc[cls=j&1][t*8 + 2g+(j>>1)] ----
    for (int q = tid; q < T * 16; q += THREADS) {
        int t = q >> 4, g = (q >> 2) & 3, j = q & 3;
        int unit = 2 * g + (j >> 1), cls = j & 1;
        ((float*)s_wfc)[q] = W_fc[cls * (T * 8) + t * 8 + unit];
    }

    // ---- pack A fragments (hi in k0-15 lanes, lo in k16-31 lanes) + bias ----
    const int au = e >> 1, ap = e & 1;
    const int row0 = ap * 8 + au;           // i (p=0) or f (p=1)
    const int row1 = 16 + ap * 8 + au;      // g (p=0) or o (p=1)
    const float sc1 = ap ? SCL_SIG : SCL_TANH;
    short8v A0, A1;
    #pragma unroll
    for (int j = 0; j < 8; ++j) {
        int k = grp * 8 + j;
        int kk = k & 15;
        float w0 = 0.f, w1 = 0.f;
        if (kk < 5)       { w0 = W_ih[row0 * 5 + kk] * SCL_SIG; w1 = W_ih[row1 * 5 + kk] * sc1; }
        else if (kk >= 8) { w0 = W_hh[row0 * 8 + kk - 8] * SCL_SIG; w1 = W_hh[row1 * 8 + kk - 8] * sc1; }
        unsigned short b0 = f2bf(w0), b1 = f2bf(w1);
        if (k >= 16) { b0 = f2bf(w0 - bf2f(b0)); b1 = f2bf(w1 - bf2f(b1)); }
        A0[j] = (short)b0; A1[j] = (short)b1;
    }
    f32x4 bias0, bias1;
    #pragma unroll
    for (int jj = 0; jj < 4; ++jj) {
        int rc = grp * 4 + jj;
        int uc = rc >> 1, pc = rc & 1;
        int w0r = pc * 8 + uc, w1r = 16 + pc * 8 + uc;
        bias0[jj] = (b_ih[w0r] + b_hh[w0r]) * SCL_SIG;
        bias1[jj] = (b_ih[w1r] + b_hh[w1r]) * (pc ? SCL_SIG : SCL_TANH);
    }

    // ---- x staging: lane stages elem (lane>>2), timesteps 2*(lane&3)+{0,1} ----
    const int es = lane >> 2;
    const int rr = lane & 3;
    const float* xbase = x + (size_t)(blockIdx.x * EPB + wv * EPW + es) * 240 + rr * 10;
    float xr[10];

    auto loadC = [&](int c) {
        const float2* p = (const float2*)(xbase + c * 40);
        #pragma unroll
        for (int q = 0; q < 5; ++q) { float2 v = p[q]; xr[2 * q] = v.x; xr[2 * q + 1] = v.y; }
    };
    auto writeC = [&](int c) {
        int b = c & 1;
        #pragma unroll
        for (int p2 = 0; p2 < 2; ++p2) {
            int tl = 2 * rr + p2;
            unsigned short hb[5], lb[5];
            #pragma unroll
            for (int q = 0; q < 5; ++q) {
                float f = xr[p2 * 5 + q];
                hb[q] = f2bf(f);
                lb[q] = f2bf(f - bf2f(hb[q]));
            }
            uint2 hv = { (unsigned)hb[0] | ((unsigned)hb[1] << 16),
                         (unsigned)hb[2] | ((unsigned)hb[3] << 16) };
            uint2 lv = { (unsigned)lb[0] | ((unsigned)lb[1] << 16),
                         (unsigned)lb[2] | ((unsigned)lb[3] << 16) };
            *(uint2*)&s_xh[wv][b][tl][es][0] = hv;
            *(unsigned*)&s_xh[wv][b][tl][es][4] = (unsigned)hb[4];
            *(uint2*)&s_xl[wv][b][tl][es][0] = lv;
            *(unsigned*)&s_xl[wv][b][tl][es][4] = (unsigned)lb[4];
        }
    };

    loadC(0);
    writeC(0);
    __syncthreads();    // s_wfc visibility (x/h are wave-private)

    const bool isX = (grp & 1) == 0;    // grp 0,2 read x frags; grp 1,3 read h frags
    float c0 = 0.f, c1 = 0.f, h0, h1, acc0 = 0.f, acc1 = 0.f;

    #pragma unroll 1
    for (int c = 0; c < NCH; ++c) {
        if (c + 1 < NCH) loadC(c + 1);
        const int b = c & 1;
        const unsigned short* pH;
        const unsigned short* pL;
        int stepB;
        if (isX) { pH = &s_xh[wv][b][0][e][0]; pL = &s_xl[wv][b][0][e][0]; stepB = EPW * 8; }
        else     { pH = &s_hh[wv][e][0];       pL = &s_hl[wv][e][0];       stepB = 0; }

        #pragma unroll
        for (int u = 0; u < CH; ++u) {
            union { short8v v; u32x4 q; } bh, bl;
            bh.q = *(const u32x4*)pH;
            bl.q = *(const u32x4*)pL;

            f32x4 g0 = __builtin_amdgcn_mfma_f32_16x16x32_bf16(A0, bh.v, bias0, 0, 0, 0);
            f32x4 g1 = __builtin_amdgcn_mfma_f32_16x16x32_bf16(A1, bh.v, bias1, 0, 0, 0);
            g0 = __builtin_amdgcn_mfma_f32_16x16x32_bf16(A0, bl.v, g0, 0, 0, 0);
            g1 = __builtin_amdgcn_mfma_f32_16x16x32_bf16(A1, bl.v, g1, 0, 0, 0);

            unitstep(EXP2F(g0[0]), EXP2F(g0[1]), EXP2F(g1[0]), EXP2F(g1[1]), c0, h0);
            unitstep(EXP2F(g0[2]), EXP2F(g0[3]), EXP2F(g1[2]), EXP2F(g1[3]), c1, h1);

            // publish h (hi + lo) for next step's B-frags
            unsigned short hh0 = f2bf(h0), hh1 = f2bf(h1);
            unsigned short hl0 = f2bf(h0 - bf2f(hh0)), hl1 = f2bf(h1 - bf2f(hh1));
            *(unsigned*)&s_hh[wv][e][2 * grp] = (unsigned)hh0 | ((unsigned)hh1 << 16);
            *(unsigned*)&s_hl[wv][e][2 * grp] = (unsigned)hl0 | ((unsigned)hl1 << 16);

            f32x4 wf = *(const f32x4*)&s_wfc[c * CH + u][grp][0];
            acc0 = fmaf(wf[0], h0, acc0);
            acc1 = fmaf(wf[1], h0, acc1);
            acc0 = fmaf(wf[2], h1, acc0);
            acc1 = fmaf(wf[3], h1, acc1);

            pH += stepB; pL += stepB;
        }
        if (c + 1 < NCH) writeC(c + 1);
    }

    // ---- reduce FC partials across the 4 grps (lanes e, e+16, e+32, e+48) ----
    acc0 += __shfl_xor(acc0, 16); acc0 += __shfl_xor(acc0, 32);
    acc1 += __shfl_xor(acc1, 16); acc1 += __shfl_xor(acc1, 32);
    if (grp == 0) {
        int gb = blockIdx.x * EPB + wv * EPW + e;
        float2 o;
        o.x = acc0 + b_fc[0];
        o.y = acc1 + b_fc[1];
        *(float2*)&out[(size_t)gb * 2] = o;
    }
}

extern "C" void kernel_launch(void* const* d_in, const int* in_sizes, int n_in,
                              void* d_out, int out_size, void* d_ws, size_t ws_size,
                              hipStream_t stream) {
    const float* x    = (const float*)d_in[0];
    const float* W_ih = (const float*)d_in[1];
    const float* W_hh = (const float*)d_in[2];
    const float* b_ih = (const float*)d_in[3];
    const float* b_hh = (const float*)d_in[4];
    const float* W_fc = (const float*)d_in[5];
    const float* b_fc = (const float*)d_in[6];
    float* out = (float*)d_out;

    const int B = in_sizes[0] / 240;        // 131072
    dim3 grid(B / EPB), block(THREADS);
    lstm_mfma<<<grid, block, 0, stream>>>(x, W_ih, W_hh, b_ih, b_hh, W_fc, b_fc, out);
}